// Round 1
// baseline (785.954 us; speedup 1.0000x reference)
//
#include <hip/hip_runtime.h>
#include <hip/hip_bf16.h>
#include <math.h>

// Problem constants
#define DM    1024          // d_model
#define NE    8             // experts
#define DF    4096          // d_ff
#define NT    4096          // tokens = B*S = 2*2048
#define RCAP  9216          // padded row capacity: 8192 + 8*128
#define OUT_N   (NT*DM)     // 4,194,304
#define DISP_N  (NT*NE)     // 32,768
#define TOTAL_OUT (OUT_N + DISP_N + NE)

typedef __attribute__((ext_vector_type(4))) float f32x4;
typedef __attribute__((ext_vector_type(8))) short bf16x8;

// ---------------- ws layout (bytes) ----------------
#define WS_CNT    0            // int[8]
#define WS_FILL   32           // int[8]
#define WS_OFFS   64           // int[9]
#define WS_TOK    128          // int[RCAP]
#define WS_WGT    (WS_TOK + RCAP*4)          // float[RCAP]
#define WS_TOPE   (WS_WGT + RCAP*4)          // int[NT*2]
#define WS_TOPV   (WS_TOPE + NT*2*4)         // float[NT*2]
#define WS_W1T    (((WS_TOPV + NT*2*4) + 255) & ~255ul)   // bf16[NE][DF][DM]
#define WS_W2T    (WS_W1T + (size_t)NE*DF*DM*2)           // bf16[NE][DM][DF]
#define WS_XG     (WS_W2T + (size_t)NE*DM*DF*2)           // bf16[RCAP][DM]
#define WS_H      (WS_XG  + (size_t)RCAP*DM*2)            // bf16[RCAP][DF]

__device__ __forceinline__ void async_copy16(const __hip_bfloat16* g, __hip_bfloat16* l) {
    __builtin_amdgcn_global_load_lds(
        (const __attribute__((address_space(1))) unsigned int*)g,
        (__attribute__((address_space(3))) unsigned int*)l, 16, 0, 0);
}

// ---------------- init: zero d_out, reset routing scratch ----------------
__global__ void init_kernel(float* __restrict__ out, int* __restrict__ cnt,
                            int* __restrict__ fill, int* __restrict__ tok) {
    int gid = blockIdx.x * blockDim.x + threadIdx.x;
    int stride = gridDim.x * blockDim.x;
    for (int i = gid; i < TOTAL_OUT; i += stride) out[i] = 0.0f;
    if (gid < RCAP) tok[gid] = -1;
    if (gid < NE) { cnt[gid] = 0; fill[gid] = 0; }
}

// ---------------- transpose+cast: in[e][R][C] f32 -> out[e][C][R] bf16 ----------------
__global__ void transpose_cast(const float* __restrict__ in, __hip_bfloat16* __restrict__ outp,
                               int R, int C) {
    __shared__ float tile[32][33];
    int e = blockIdx.z;
    int c0 = blockIdx.x * 32, r0 = blockIdx.y * 32;
    const float* ib = in + (size_t)e * R * C;
    __hip_bfloat16* ob = outp + (size_t)e * R * C;
    int tx = threadIdx.x & 31, ty = threadIdx.x >> 5;   // 32 x 8
    for (int rr = ty; rr < 32; rr += 8)
        tile[rr][tx] = ib[(size_t)(r0 + rr) * C + c0 + tx];
    __syncthreads();
    for (int cc = ty; cc < 32; cc += 8)
        ob[(size_t)(c0 + cc) * R + r0 + tx] = __float2bfloat16(tile[tx][cc]);
}

// ---------------- gating: 1 wave per token, f64 logits ----------------
__global__ void gate_kernel(const float* __restrict__ x, const float* __restrict__ gw,
                            const float* __restrict__ gb, float* __restrict__ disp,
                            float* __restrict__ counts, int* __restrict__ cnt,
                            int* __restrict__ tope, float* __restrict__ topv) {
    int t = blockIdx.x;
    int l = threadIdx.x;   // 64
    const float* xr = x + (size_t)t * DM;
    double p[NE];
    #pragma unroll
    for (int e = 0; e < NE; ++e) p[e] = 0.0;
    for (int i = 0; i < DM / 64; ++i) {
        int d = l + 64 * i;
        double xv = (double)xr[d];
        const float* gr = gw + (size_t)d * NE;
        #pragma unroll
        for (int e = 0; e < NE; ++e) p[e] += xv * (double)gr[e];
    }
    #pragma unroll
    for (int off = 32; off > 0; off >>= 1) {
        #pragma unroll
        for (int e = 0; e < NE; ++e) p[e] += __shfl_xor(p[e], off, 64);
    }
    if (l == 0) {
        double lg[NE];
        double m = -1e300;
        #pragma unroll
        for (int e = 0; e < NE; ++e) { lg[e] = p[e] + (double)gb[e]; m = fmax(m, lg[e]); }
        double s = 0.0;
        #pragma unroll
        for (int e = 0; e < NE; ++e) s += exp(lg[e] - m);
        int e1 = 0;
        #pragma unroll
        for (int e = 1; e < NE; ++e) if (lg[e] > lg[e1]) e1 = e;
        int e2 = (e1 == 0) ? 1 : 0;
        #pragma unroll
        for (int e = 0; e < NE; ++e) if (e != e1 && lg[e] > lg[e2]) e2 = e;
        float v1 = (float)(exp(lg[e1] - m) / s);
        float v2 = (float)(exp(lg[e2] - m) / s);
        float* dr = disp + (size_t)t * NE;
        #pragma unroll
        for (int e = 0; e < NE; ++e) dr[e] = 0.0f;
        dr[e1] = v1; dr[e2] = v2;
        atomicAdd(&counts[e1], v1);
        atomicAdd(&counts[e2], v2);
        atomicAdd(&cnt[e1], 1);
        atomicAdd(&cnt[e2], 1);
        tope[2 * t] = e1;     topv[2 * t] = v1;
        tope[2 * t + 1] = e2; topv[2 * t + 1] = v2;
    }
}

// ---------------- scan: 128-aligned exclusive prefix ----------------
__global__ void scan_kernel(const int* __restrict__ cnt, int* __restrict__ offs) {
    if (threadIdx.x == 0 && blockIdx.x == 0) {
        int o = 0;
        for (int e = 0; e < NE; ++e) {
            offs[e] = o;
            o += (cnt[e] + 127) & ~127;
        }
        offs[NE] = o;
    }
}

// ---------------- build per-expert row lists ----------------
__global__ void build_kernel(const int* __restrict__ tope, const float* __restrict__ topv,
                             const int* __restrict__ offs, int* __restrict__ fill,
                             int* __restrict__ tok, float* __restrict__ wgt) {
    int t = blockIdx.x * blockDim.x + threadIdx.x;
    if (t >= NT) return;
    #pragma unroll
    for (int s = 0; s < 2; ++s) {
        int e = tope[2 * t + s];
        int pos = atomicAdd(&fill[e], 1);
        int row = offs[e] + pos;
        tok[row] = t;
        wgt[row] = topv[2 * t + s];
    }
}

// ---------------- gather x rows -> bf16 ----------------
__global__ void gather_kernel(const float* __restrict__ x, const int* __restrict__ tok,
                              __hip_bfloat16* __restrict__ xg) {
    int row = blockIdx.x;
    int t = tok[row];
    if (t < 0) return;
    int i = threadIdx.x;   // 256, 4 elems each
    const float4 v = ((const float4*)(x + (size_t)t * DM))[i];
    ushort4 o;
    o.x = __bfloat16_as_ushort(__float2bfloat16(v.x));
    o.y = __bfloat16_as_ushort(__float2bfloat16(v.y));
    o.z = __bfloat16_as_ushort(__float2bfloat16(v.z));
    o.w = __bfloat16_as_ushort(__float2bfloat16(v.w));
    ((ushort4*)(xg + (size_t)row * DM))[i] = o;
}

// ---------------- GEMM core macro pieces (128x128 tile, BK=32, 4 waves) ----------------
// A: bf16 [rows][K] row-major; B: bf16 [N][K] row-major (pre-transposed)

// GEMM1: h = gelu(xg @ w1 + b1), K=DM, N=DF
__global__ __launch_bounds__(256) void gemm1_kernel(
    const __hip_bfloat16* __restrict__ xg, const __hip_bfloat16* __restrict__ w1t,
    const float* __restrict__ b1, __hip_bfloat16* __restrict__ h,
    const int* __restrict__ offs, const int* __restrict__ cnt) {
    __shared__ __hip_bfloat16 As[128 * 32];
    __shared__ __hip_bfloat16 Bs[128 * 32];
    const int row0 = blockIdx.y * 128;
    const int total = offs[NE];
    if (row0 >= total) return;
    int e = 0;
    while (row0 >= offs[e + 1]) ++e;
    if (row0 >= offs[e] + cnt[e]) return;   // tile entirely padding
    const int n0 = blockIdx.x * 128;
    const __hip_bfloat16* Ab = xg + (size_t)row0 * DM;
    const __hip_bfloat16* Bb = w1t + (size_t)e * DF * DM + (size_t)n0 * DM;

    const int tid = threadIdx.x, lane = tid & 63, wave = tid >> 6;
    const int wm = wave >> 1, wn = wave & 1, g = lane >> 4, r = lane & 15;
    const int c1 = tid, c2 = tid + 256;

    f32x4 acc[4][4];
    #pragma unroll
    for (int m = 0; m < 4; ++m)
        #pragma unroll
        for (int n = 0; n < 4; ++n)
            #pragma unroll
            for (int j = 0; j < 4; ++j) acc[m][n][j] = 0.0f;

    for (int k0 = 0; k0 < DM; k0 += 32) {
        async_copy16(Ab + (size_t)(c1 >> 2) * DM + k0 + (c1 & 3) * 8, As + c1 * 8);
        async_copy16(Ab + (size_t)(c2 >> 2) * DM + k0 + (c2 & 3) * 8, As + c2 * 8);
        async_copy16(Bb + (size_t)(c1 >> 2) * DM + k0 + (c1 & 3) * 8, Bs + c1 * 8);
        async_copy16(Bb + (size_t)(c2 >> 2) * DM + k0 + (c2 & 3) * 8, Bs + c2 * 8);
        __syncthreads();
        bf16x8 af[4], bfr[4];
        #pragma unroll
        for (int m = 0; m < 4; ++m)
            af[m] = *(const bf16x8*)(As + (wm * 64 + m * 16 + r) * 32 + g * 8);
        #pragma unroll
        for (int n = 0; n < 4; ++n)
            bfr[n] = *(const bf16x8*)(Bs + (wn * 64 + n * 16 + r) * 32 + g * 8);
        #pragma unroll
        for (int m = 0; m < 4; ++m)
            #pragma unroll
            for (int n = 0; n < 4; ++n)
                acc[m][n] = __builtin_amdgcn_mfma_f32_16x16x32_bf16(af[m], bfr[n], acc[m][n], 0, 0, 0);
        __syncthreads();
    }
    // epilogue: bias + exact gelu -> bf16 h
    float bb[4];
    #pragma unroll
    for (int n = 0; n < 4; ++n) bb[n] = b1[(size_t)e * DF + n0 + wn * 64 + n * 16 + r];
    #pragma unroll
    for (int m = 0; m < 4; ++m) {
        #pragma unroll
        for (int i = 0; i < 4; ++i) {
            int rowi = row0 + wm * 64 + m * 16 + g * 4 + i;
            __hip_bfloat16* hr = h + (size_t)rowi * DF + n0 + wn * 64 + r;
            #pragma unroll
            for (int n = 0; n < 4; ++n) {
                float v = acc[m][n][i] + bb[n];
                float ge = 0.5f * v * (1.0f + erff(v * 0.70710678118654752f));
                hr[n * 16] = __float2bfloat16(ge);
            }
        }
    }
}

// GEMM2: out[t] += v * (h @ w2 + b2), K=DF, N=DM
__global__ __launch_bounds__(256) void gemm2_kernel(
    const __hip_bfloat16* __restrict__ h, const __hip_bfloat16* __restrict__ w2t,
    const float* __restrict__ b2, float* __restrict__ out,
    const int* __restrict__ offs, const int* __restrict__ cnt,
    const int* __restrict__ tok, const float* __restrict__ wgt) {
    __shared__ __hip_bfloat16 As[128 * 32];
    __shared__ __hip_bfloat16 Bs[128 * 32];
    const int row0 = blockIdx.y * 128;
    const int total = offs[NE];
    if (row0 >= total) return;
    int e = 0;
    while (row0 >= offs[e + 1]) ++e;
    if (row0 >= offs[e] + cnt[e]) return;
    const int n0 = blockIdx.x * 128;
    const __hip_bfloat16* Ab = h + (size_t)row0 * DF;
    const __hip_bfloat16* Bb = w2t + (size_t)e * DM * DF + (size_t)n0 * DF;

    const int tid = threadIdx.x, lane = tid & 63, wave = tid >> 6;
    const int wm = wave >> 1, wn = wave & 1, g = lane >> 4, r = lane & 15;
    const int c1 = tid, c2 = tid + 256;

    f32x4 acc[4][4];
    #pragma unroll
    for (int m = 0; m < 4; ++m)
        #pragma unroll
        for (int n = 0; n < 4; ++n)
            #pragma unroll
            for (int j = 0; j < 4; ++j) acc[m][n][j] = 0.0f;

    for (int k0 = 0; k0 < DF; k0 += 32) {
        async_copy16(Ab + (size_t)(c1 >> 2) * DF + k0 + (c1 & 3) * 8, As + c1 * 8);
        async_copy16(Ab + (size_t)(c2 >> 2) * DF + k0 + (c2 & 3) * 8, As + c2 * 8);
        async_copy16(Bb + (size_t)(c1 >> 2) * DF + k0 + (c1 & 3) * 8, Bs + c1 * 8);
        async_copy16(Bb + (size_t)(c2 >> 2) * DF + k0 + (c2 & 3) * 8, Bs + c2 * 8);
        __syncthreads();
        bf16x8 af[4], bfr[4];
        #pragma unroll
        for (int m = 0; m < 4; ++m)
            af[m] = *(const bf16x8*)(As + (wm * 64 + m * 16 + r) * 32 + g * 8);
        #pragma unroll
        for (int n = 0; n < 4; ++n)
            bfr[n] = *(const bf16x8*)(Bs + (wn * 64 + n * 16 + r) * 32 + g * 8);
        #pragma unroll
        for (int m = 0; m < 4; ++m)
            #pragma unroll
            for (int n = 0; n < 4; ++n)
                acc[m][n] = __builtin_amdgcn_mfma_f32_16x16x32_bf16(af[m], bfr[n], acc[m][n], 0, 0, 0);
        __syncthreads();
    }
    // epilogue: weighted scatter-add with bias
    float bb[4];
    #pragma unroll
    for (int n = 0; n < 4; ++n) bb[n] = b2[(size_t)e * DM + n0 + wn * 64 + n * 16 + r];
    #pragma unroll
    for (int m = 0; m < 4; ++m) {
        #pragma unroll
        for (int i = 0; i < 4; ++i) {
            int rowi = row0 + wm * 64 + m * 16 + g * 4 + i;
            int t = tok[rowi];
            if (t < 0) continue;
            float wv = wgt[rowi];
            float* orow = out + (size_t)t * DM + n0 + wn * 64 + r;
            #pragma unroll
            for (int n = 0; n < 4; ++n)
                atomicAdd(orow + n * 16, wv * (acc[m][n][i] + bb[n]));
        }
    }
}

// ---------------- launch ----------------
extern "C" void kernel_launch(void* const* d_in, const int* in_sizes, int n_in,
                              void* d_out, int out_size, void* d_ws, size_t ws_size,
                              hipStream_t stream) {
    const float* x  = (const float*)d_in[0];
    const float* gw = (const float*)d_in[1];
    const float* gb = (const float*)d_in[2];
    const float* w1 = (const float*)d_in[3];
    const float* b1 = (const float*)d_in[4];
    const float* w2 = (const float*)d_in[5];
    const float* b2 = (const float*)d_in[6];

    float* out    = (float*)d_out;           // [NT*DM]
    float* disp   = out + OUT_N;             // [NT*NE]
    float* counts = disp + DISP_N;           // [NE]

    char* ws = (char*)d_ws;
    int*   cnt  = (int*)(ws + WS_CNT);
    int*   fill = (int*)(ws + WS_FILL);
    int*   offs = (int*)(ws + WS_OFFS);
    int*   tok  = (int*)(ws + WS_TOK);
    float* wgt  = (float*)(ws + WS_WGT);
    int*   tope = (int*)(ws + WS_TOPE);
    float* topv = (float*)(ws + WS_TOPV);
    __hip_bfloat16* w1t = (__hip_bfloat16*)(ws + WS_W1T);
    __hip_bfloat16* w2t = (__hip_bfloat16*)(ws + WS_W2T);
    __hip_bfloat16* xg  = (__hip_bfloat16*)(ws + WS_XG);
    __hip_bfloat16* h   = (__hip_bfloat16*)(ws + WS_H);

    init_kernel<<<4096, 256, 0, stream>>>(out, cnt, fill, tok);
    // w1: per-expert [DM][DF] -> [DF][DM]
    transpose_cast<<<dim3(DF / 32, DM / 32, NE), 256, 0, stream>>>(w1, w1t, DM, DF);
    // w2: per-expert [DF][DM] -> [DM][DF]
    transpose_cast<<<dim3(DM / 32, DF / 32, NE), 256, 0, stream>>>(w2, w2t, DF, DM);
    gate_kernel<<<NT, 64, 0, stream>>>(x, gw, gb, disp, counts, cnt, tope, topv);
    scan_kernel<<<1, 64, 0, stream>>>(cnt, offs);
    build_kernel<<<NT / 256, 256, 0, stream>>>(tope, topv, offs, fill, tok, wgt);
    gather_kernel<<<RCAP, 256, 0, stream>>>(x, tok, xg);
    gemm1_kernel<<<dim3(DF / 128, RCAP / 128), 256, 0, stream>>>(xg, w1t, b1, h, offs, cnt);
    gemm2_kernel<<<dim3(DM / 128, RCAP / 128), 256, 0, stream>>>(h, w2t, b2, out, offs, cnt, tok, wgt);
}